// Round 6
// baseline (313.334 us; speedup 1.0000x reference)
//
#include <hip/hip_runtime.h>
#include <math.h>

// BundleAdjustmentModel: project N 3D points into V=64 camera views.
// out[v][n] = (u,v), u = -f*X/safe_z + cx, v = f*Y/safe_z + cy,
// [X,Y,Z] = R_v * p_n + t_v, R_v = Rx*Ry*Rz (euler xyz), t_v = (tx,ty,-(softplus(d)+0.25))
//
// Counter-backed evidence so far:
//  - dur_us ~= poison_fill(155us, 1GB @6.6TB/s) + kernel. Kernel floor = 40us
//    (256MB writes at fill rate); best kernel so far ~105us (~2.5 TB/s).
//  - NT stores: 2.63x write amplification (WRITE_SIZE 674MB) -> never again.
//  - FETCH_SIZE ~23MB even with 64x point re-read: L3 absorbs reads.
//  - Store instruction width/count per wave: NO effect (r5 A/B, 261.2 vs 260.5).
//  - Fill achieves 6.6 TB/s at 10% occupancy / 8 VGPR -> only the AGGREGATE
//    store address stream distinguishes it from us.
// Hypothesis under test (single variable vs measured round 4 = 304.5us):
//  grid order. Round 4 used grid(view, chunk) -> view fastest-varying -> the
//  ~2048 resident blocks spanned all 64 output rows -> scattered 16KB bursts,
//  DRAM row-buffer thrash. This version swaps to grid(chunk, view): dispatch
//  is chunk-major, so resident blocks write a few CONSECUTIVE rows as
//  contiguous multi-MB sweeps -- fill-like global write linearity.
//
// Structure (identical to round 4 otherwise):
//  - ONE view per block (blockIdx.y); view constants in registers; no LDS.
//  - PPT=8 consecutive points/thread: 6x global_load_dwordx4 in, ~120 VALU,
//    4x plain global_store_dwordx4 out; block writes one contiguous 16KB span.

#define NVIEW 64
#define BLOCK 256
#define PPT 8            // consecutive points per thread
#define Z_EPS 1e-4f

__device__ __forceinline__ float softplus_f(float x) {
    // stable: max(x,0) + log1p(exp(-|x|))
    return fmaxf(x, 0.0f) + log1pf(expf(-fabsf(x)));
}

__global__ __launch_bounds__(BLOCK) void ba_project_kernel(
    const float* __restrict__ points,          // (N,3)
    const float* __restrict__ euler,           // (V,3)
    const float* __restrict__ txy,             // (V,2)
    const float* __restrict__ tdr,             // (V,)
    const float* __restrict__ focal_raw,       // (1,)
    const int*   __restrict__ cxp,             // (1,)
    const int*   __restrict__ cyp,             // (1,)
    float2* __restrict__ out,                  // (V,N) float2
    int N)
{
    const int v = blockIdx.y;                  // one view per block (slow axis!)

    // ---- per-view constants, all wave-uniform, all in registers ----
    const float focal = softplus_f(focal_raw[0]) + 50.0f;

    float ex = euler[v * 3 + 0];
    float ey = euler[v * 3 + 1];
    float ez = euler[v * 3 + 2];
    float sx, cx_, sy, cy_, sz, cz;
    sincosf(ex, &sx, &cx_);
    sincosf(ey, &sy, &cy_);
    sincosf(ez, &sz, &cz);
    // R = Rx @ Ry @ Rz
    float r00 = cy_ * cz;
    float r01 = -cy_ * sz;
    float r02 = sy;
    float r10 = cx_ * sz + sx * sy * cz;
    float r11 = cx_ * cz - sx * sy * sz;
    float r12 = -sx * cy_;
    float r20 = sx * sz - cx_ * sy * cz;
    float r21 = sx * cz + cx_ * sy * sz;
    float r22 = cx_ * cy_;

    float tx = txy[v * 2 + 0];
    float ty = txy[v * 2 + 1];
    float tz = -(softplus_f(tdr[v]) + 0.25f);

    // fold focal + sign: u = (-f*R0.p + -f*tx)/safe_z + cx ; v-row = +f*R1
    const float a0 = -focal * r00, a1 = -focal * r01, a2 = -focal * r02, a3 = -focal * tx;
    const float b0 =  focal * r10, b1 =  focal * r11, b2 =  focal * r12, b3 =  focal * ty;
    const float ccx = (float)cxp[0];
    const float ccy = (float)cyp[0];

    const int n0 = (blockIdx.x * BLOCK + threadIdx.x) * PPT;
    if (n0 >= N) return;

    float2* orow = out + (size_t)v * N + n0;

    if (n0 + PPT <= N) {
        // fast path: 8 consecutive points = 24 floats = 6 aligned float4 loads
        // (byte offset n0*12 = 96*t, multiple of 16)
        const float4* src = (const float4*)(points + (size_t)n0 * 3);
        float4 L0 = src[0], L1 = src[1], L2 = src[2];
        float4 L3 = src[3], L4 = src[4], L5 = src[5];
        const float P[PPT][3] = {
            {L0.x, L0.y, L0.z}, {L0.w, L1.x, L1.y},
            {L1.z, L1.w, L2.x}, {L2.y, L2.z, L2.w},
            {L3.x, L3.y, L3.z}, {L3.w, L4.x, L4.y},
            {L4.z, L4.w, L5.x}, {L5.y, L5.z, L5.w}};

        float uv[PPT * 2];
#pragma unroll
        for (int k = 0; k < PPT; ++k) {
            float X = fmaf(a0, P[k][0], fmaf(a1, P[k][1], fmaf(a2, P[k][2], a3)));
            float Y = fmaf(b0, P[k][0], fmaf(b1, P[k][1], fmaf(b2, P[k][2], b3)));
            float Z = fmaf(r20, P[k][0], fmaf(r21, P[k][1], fmaf(r22, P[k][2], tz)));
            float sg = (Z >= 0.0f) ? 1.0f : -1.0f;
            float t  = __builtin_amdgcn_rcpf(sg * fmaxf(fabsf(Z), Z_EPS));
            uv[k * 2 + 0] = fmaf(X, t, ccx);
            uv[k * 2 + 1] = fmaf(Y, t, ccy);
        }

        // 4x plain dwordx4 stores: wave writes 4KB contiguous, full lines.
        float4* o4 = (float4*)orow;
#pragma unroll
        for (int k = 0; k < PPT / 2; ++k) {
            o4[k] = make_float4(uv[4 * k + 0], uv[4 * k + 1],
                                uv[4 * k + 2], uv[4 * k + 3]);
        }
    } else {
        // tail path (unused for N=500000, kept general)
        for (int k = 0; k < PPT && n0 + k < N; ++k) {
            float x = points[(size_t)(n0 + k) * 3 + 0];
            float y = points[(size_t)(n0 + k) * 3 + 1];
            float z = points[(size_t)(n0 + k) * 3 + 2];
            float X = fmaf(a0, x, fmaf(a1, y, fmaf(a2, z, a3)));
            float Y = fmaf(b0, x, fmaf(b1, y, fmaf(b2, z, b3)));
            float Z = fmaf(r20, x, fmaf(r21, y, fmaf(r22, z, tz)));
            float sg = (Z >= 0.0f) ? 1.0f : -1.0f;
            float t  = __builtin_amdgcn_rcpf(sg * fmaxf(fabsf(Z), Z_EPS));
            orow[k] = make_float2(fmaf(X, t, ccx), fmaf(Y, t, ccy));
        }
    }
}

extern "C" void kernel_launch(void* const* d_in, const int* in_sizes, int n_in,
                              void* d_out, int out_size, void* d_ws, size_t ws_size,
                              hipStream_t stream) {
    const float* points    = (const float*)d_in[0];
    const float* euler     = (const float*)d_in[1];
    const float* txy       = (const float*)d_in[2];
    const float* tdr       = (const float*)d_in[3];
    const float* focal_raw = (const float*)d_in[4];
    const int*   cxp       = (const int*)d_in[5];
    const int*   cyp       = (const int*)d_in[6];

    const int N = in_sizes[0] / 3;
    const int chunk = BLOCK * PPT;                       // 2048 points per block
    const int nchunks = (N + chunk - 1) / chunk;
    dim3 grid(nchunks, NVIEW, 1);                        // chunk-major dispatch

    ba_project_kernel<<<grid, dim3(BLOCK, 1, 1), 0, stream>>>(
        points, euler, txy, tdr, focal_raw, cxp, cyp, (float2*)d_out, N);
}

// Round 7
// 260.009 us; speedup vs baseline: 1.2051x; 1.2051x over previous
//
#include <hip/hip_runtime.h>
#include <math.h>

// BundleAdjustmentModel: project N 3D points into V=64 camera views.
// out[v][n] = (u,v), u = -f*X/safe_z + cx, v = f*Y/safe_z + cy,
// [X,Y,Z] = R_v * p_n + t_v, R_v = Rx*Ry*Rz (euler xyz), t_v = (tx,ty,-(softplus(d)+0.25))
//
// Counter-backed ledger:
//  - dur_us ~= poison_fill(155us) + kernel. Write floor = 40us (256MB @ fill's
//    6.6 TB/s). Best kernel: the 64-view in-thread loop, ~105us.
//  - NT stores: 2.63x write amplification -> never.
//  - FETCH_SIZE ~23MB even at 64x re-read: L3 absorbs reads; but kernel time
//    scales with re-read volume -> keep points loaded ONCE (this structure).
//  - Store width per wave (2x8B vs 1x16B): no effect (r5).
//  - Aggregate store-stream linearity (chunk-major 1-view/block): no effect
//    (r6 = 313 vs r4 = 304) -> DRAM row-thrash theory falsified.
//  => remaining theory: PER-WAVE SERIALIZATION. The un-unrolled view loop
//     reuses the same registers every iteration, forcing s_waitcnt
//     vmcnt/lgkmcnt fences per view: wall per iter ~ LDS+store latency
//     (~300-500cy) instead of ~80cy of pipe time.
// This round (single variable vs r5): UNROLL the view loop x4 -> 4 independent
// ds_read triplets / compute chains / outstanding stores between fences.

#define NVIEW 64
#define BLOCK 256
#define Z_EPS 1e-4f

__device__ __forceinline__ float softplus_f(float x) {
    // stable: max(x,0) + log1p(exp(-|x|))
    return fmaxf(x, 0.0f) + log1pf(expf(-fabsf(x)));
}

__global__ __launch_bounds__(BLOCK) void ba_project_kernel(
    const float* __restrict__ points,          // (N,3)
    const float* __restrict__ euler,           // (V,3)
    const float* __restrict__ txy,             // (V,2)
    const float* __restrict__ tdr,             // (V,)
    const float* __restrict__ focal_raw,       // (1,)
    const int*   __restrict__ cxp,             // (1,)
    const int*   __restrict__ cyp,             // (1,)
    float2* __restrict__ out,                  // (V,N) float2
    int N)
{
    // Per-view constants: rows [-f*R0|-f*tx], [f*R1|f*ty], [R2|tz],
    // 3 float4s per view. Broadcast ds_read_b128 -> conflict-free.
    __shared__ float4 vd[NVIEW * 3];

    const int tid = threadIdx.x;
    const float focal = softplus_f(focal_raw[0]) + 50.0f;

    if (tid < NVIEW) {
        float ex = euler[tid * 3 + 0];
        float ey = euler[tid * 3 + 1];
        float ez = euler[tid * 3 + 2];
        float sx, cx_, sy, cy_, sz, cz;
        sincosf(ex, &sx, &cx_);
        sincosf(ey, &sy, &cy_);
        sincosf(ez, &sz, &cz);
        // R = Rx @ Ry @ Rz
        float r00 = cy_ * cz;
        float r01 = -cy_ * sz;
        float r02 = sy;
        float r10 = cx_ * sz + sx * sy * cz;
        float r11 = cx_ * cz - sx * sy * sz;
        float r12 = -sx * cy_;
        float r20 = sx * sz - cx_ * sy * cz;
        float r21 = sx * cz + cx_ * sy * sz;
        float r22 = cx_ * cy_;

        float tx = txy[tid * 2 + 0];
        float ty = txy[tid * 2 + 1];
        float tz = -(softplus_f(tdr[tid]) + 0.25f);

        vd[tid * 3 + 0] = make_float4(-focal * r00, -focal * r01, -focal * r02, -focal * tx);
        vd[tid * 3 + 1] = make_float4( focal * r10,  focal * r11,  focal * r12,  focal * ty);
        vd[tid * 3 + 2] = make_float4(r20, r21, r22, tz);
    }
    __syncthreads();

    const float ccx = (float)cxp[0];
    const float ccy = (float)cyp[0];

    // Each thread owns the consecutive point pair {2*pair, 2*pair+1};
    // points loaded ONCE, reused across all 64 views.
    const int pair = blockIdx.x * BLOCK + tid;
    const int n0 = pair * 2;
    if (n0 >= N) return;
    const bool full = (n0 + 1 < N);   // N=500000 even; guard stays general

    const float2* p2 = (const float2*)points;   // 8B-aligned pair loads
    float2 a = p2[pair * 3 + 0];
    float2 b, c;
    if (full) {
        b = p2[pair * 3 + 1];
        c = p2[pair * 3 + 2];
    } else {
        b = make_float2(points[(size_t)n0 * 3 + 2], 0.0f);  // z0 only, no OOB
        c = make_float2(0.0f, 0.0f);
    }
    const float x0 = a.x, y0 = a.y, z0 = b.x;
    const float x1 = b.y, y1 = c.x, z1 = c.y;

    float2* orow = out + n0;   // + v*N added per iteration

    // Unroll x4: 4 independent {ds_read x3, FMA chain, rcp, store} bodies
    // between waitcnt fences -> 4 outstanding stores, 12 outstanding ds_reads,
    // amortizing per-iteration latency 4x.
#pragma unroll 4
    for (int v = 0; v < NVIEW; ++v) {
        float4 A = vd[v * 3 + 0];
        float4 B = vd[v * 3 + 1];
        float4 C = vd[v * 3 + 2];

        // point 0
        float X0 = fmaf(A.x, x0, fmaf(A.y, y0, fmaf(A.z, z0, A.w)));
        float Y0 = fmaf(B.x, x0, fmaf(B.y, y0, fmaf(B.z, z0, B.w)));
        float Z0 = fmaf(C.x, x0, fmaf(C.y, y0, fmaf(C.z, z0, C.w)));
        float sg0 = (Z0 >= 0.0f) ? 1.0f : -1.0f;
        float t0  = __builtin_amdgcn_rcpf(sg0 * fmaxf(fabsf(Z0), Z_EPS));
        float u0 = fmaf(X0, t0, ccx);
        float w0 = fmaf(Y0, t0, ccy);

        // point 1
        float X1 = fmaf(A.x, x1, fmaf(A.y, y1, fmaf(A.z, z1, A.w)));
        float Y1 = fmaf(B.x, x1, fmaf(B.y, y1, fmaf(B.z, z1, B.w)));
        float Z1 = fmaf(C.x, x1, fmaf(C.y, y1, fmaf(C.z, z1, C.w)));
        float sg1 = (Z1 >= 0.0f) ? 1.0f : -1.0f;
        float t1  = __builtin_amdgcn_rcpf(sg1 * fmaxf(fabsf(Z1), Z_EPS));
        float u1 = fmaf(X1, t1, ccx);
        float w1 = fmaf(Y1, t1, ccy);

        if (full) {
            // one 16B store per view: wave writes contiguous, 16B-aligned 1 KB
            *(float4*)(orow + (size_t)v * N) = make_float4(u0, w0, u1, w1);
        } else {
            orow[(size_t)v * N] = make_float2(u0, w0);
        }
    }
}

extern "C" void kernel_launch(void* const* d_in, const int* in_sizes, int n_in,
                              void* d_out, int out_size, void* d_ws, size_t ws_size,
                              hipStream_t stream) {
    const float* points    = (const float*)d_in[0];
    const float* euler     = (const float*)d_in[1];
    const float* txy       = (const float*)d_in[2];
    const float* tdr       = (const float*)d_in[3];
    const float* focal_raw = (const float*)d_in[4];
    const int*   cxp       = (const int*)d_in[5];
    const int*   cyp       = (const int*)d_in[6];

    const int N = in_sizes[0] / 3;
    const int pairs = (N + 1) / 2;
    const int blocks = (pairs + BLOCK - 1) / BLOCK;

    ba_project_kernel<<<blocks, dim3(BLOCK, 1, 1), 0, stream>>>(
        points, euler, txy, tdr, focal_raw, cxp, cyp, (float2*)d_out, N);
}